// Round 4
// baseline (80.166 us; speedup 1.0000x reference)
//
#include <hip/hip_runtime.h>
#include <math.h>
#include <float.h>

// ChamferLoss: set1/set2 [8, 4096, 3] fp32 -> scalar
// out = (sum of per-point min dists, both directions) / (8*4096*4096)
//
// v5: same MFMA formulation as v4 (d^2 = q^2 + (p^2 - 2 q.p) via one
// v_mfma_f32_32x32x16_bf16 per 32x32 pair tile, hi/lo bf16 split in K),
// but the inner loop is manually staggered:
//   - NO #pragma unroll (v4's unroll-4 held up to 16 live f32x16 C-sets ->
//     spill/serialization under the 128-VGPR launch_bounds cap; est. 23us)
//   - at most 2-3 live C-sets (c0/c1 ping-pong), folds interleaved between
//     MFMAs so each fold overlaps the next MFMA's execution
//   - A-frag prefetched 1 tile ahead (global->reg, L2-resident stream)
// Live regs ~100: Bf[4]=16, zero16=16, c x2..3=32..48, a+anext=8, dmin=4.
// Floors: MFMA pipe 0.85us/CU, VALU (8 v_min3/MFMA) 2.1us -> target 6-8us.

#define NTOT 65536            // 2 sets * 8 batches * 4096 points
#define NPTS 4096

typedef __attribute__((ext_vector_type(8)))  short bf16x8;
typedef __attribute__((ext_vector_type(16))) float f32x16;

__device__ __forceinline__ unsigned short f2bf(float f) {
    union { float f; unsigned u; } v; v.f = f;
    return (unsigned short)((v.u + 0x7FFFu + ((v.u >> 16) & 1u)) >> 16);
}
__device__ __forceinline__ float bf2f(unsigned short h) {
    union { unsigned u; float f; } v; v.u = ((unsigned)h) << 16;
    return v.f;
}
__device__ __forceinline__ unsigned short m2(unsigned short h) {
    return f2bf(-2.0f * bf2f(h));     // exact: exponent+1, sign flip
}
__device__ __forceinline__ unsigned pack2(unsigned a, unsigned b) {
    return (a & 0xFFFFu) | (b << 16);
}

__global__ __launch_bounds__(256)
void pack_pts(const float* __restrict__ set1, const float* __restrict__ set2,
              uint4* __restrict__ lo, uint4* __restrict__ hi,
              float* __restrict__ q2o)
{
    const int i = blockIdx.x * 256 + threadIdx.x;     // 0..65535
    const float* __restrict__ src = (i < NTOT / 2) ? set1 : set2;
    const int idx = i & (NTOT / 2 - 1);
    const float x = src[3 * idx + 0];
    const float y = src[3 * idx + 1];
    const float z = src[3 * idx + 2];
    const unsigned short xh = f2bf(x), yh = f2bf(y), zh = f2bf(z);
    const unsigned short xl = f2bf(x - bf2f(xh));
    const unsigned short yl = f2bf(y - bf2f(yh));
    const unsigned short zl = f2bf(z - bf2f(zh));
    const float p2 = fmaf(x, x, fmaf(y, y, z * z));
    const unsigned short pa = f2bf(p2);
    const float r1 = p2 - bf2f(pa);
    const unsigned short pb = f2bf(r1);
    const unsigned short pc = f2bf(r1 - bf2f(pb));
    // A-frag lo half (k0-7):  [xh,yh,zh, xl,yl,zl, xh,yh]
    lo[i] = make_uint4(pack2(xh, yh), pack2(zh, xl), pack2(yl, zl), pack2(xh, yh));
    // A-frag hi half (k8-15): [zh, xl,yl,zl, pa,pb,pc, 0]
    hi[i] = make_uint4(pack2(zh, xl), pack2(yl, zl), pack2(pa, pb), pack2(pc, 0));
    q2o[i] = p2;
}

__device__ __forceinline__ float fold16(const f32x16 c, float m) {
    // 8 x v_min3_f32
    m = fminf(fminf(c[0],  c[1]),  m);
    m = fminf(fminf(c[2],  c[3]),  m);
    m = fminf(fminf(c[4],  c[5]),  m);
    m = fminf(fminf(c[6],  c[7]),  m);
    m = fminf(fminf(c[8],  c[9]),  m);
    m = fminf(fminf(c[10], c[11]), m);
    m = fminf(fminf(c[12], c[13]), m);
    m = fminf(fminf(c[14], c[15]), m);
    return m;
}

__global__ __launch_bounds__(512, 4)
void chamfer_main(const uint4* __restrict__ lo, const uint4* __restrict__ hi,
                  const float* __restrict__ q2arr, float* __restrict__ out)
{
    __shared__ float part[8][128];        // 4 KB

    const int blk = blockIdx.x;           // 0..511
    const int dir = blk >> 8;             // 0: q=set1 db=set2, 1: swapped
    const int rem = blk & 255;
    const int b   = rem >> 5;             // batch 0..7
    const int qc  = rem & 31;             // 128-query chunk 0..31

    const int qBase  = dir * (NTOT / 2) + b * NPTS + qc * 128;
    const int dbBase = (1 - dir) * (NTOT / 2) + b * NPTS;

    const int t    = threadIdx.x;
    const int lane = t & 63;
    const int w    = t >> 6;              // wave 0..7: point eighth
    const int col  = lane & 31;
    const int half = lane >> 5;           // k-half (0: k0-7, 1: k8-15)

    // ---- B-frags: 4 query tiles, rearranged from this lane's query A-pack ----
    const uint4* __restrict__ qsrc = half ? hi : lo;
    bf16x8 Bf[4];
    #pragma unroll
    for (int j = 0; j < 4; ++j) {
        const uint4 sv = qsrc[qBase + j * 32 + col];
        const unsigned short s0 = sv.x & 0xFFFF, s1 = sv.x >> 16;
        const unsigned short s2 = sv.y & 0xFFFF, s3 = sv.y >> 16;
        const unsigned short s4 = sv.z & 0xFFFF;
        uint4 bv;
        if (!half) {
            // [-2xh,-2yh,-2zh, -2xh,-2yh,-2zh, -2xl,-2yl]
            const unsigned short a0 = m2(s0), a1 = m2(s1), a2 = m2(s2);
            bv = make_uint4(pack2(a0, a1), pack2(a2, a0),
                            pack2(a1, a2), pack2(m2(s3), m2(s4)));
        } else {
            // hi slots: s0=zh s1=xl s2=yl s3=zl ...
            // [-2zl, -2xl,-2yl,-2zl, 1,1,1, 0]
            const unsigned short a3 = m2(s3);
            const unsigned one = 0x3F80u;
            bv = make_uint4(pack2(a3, m2(s1)), pack2(m2(s2), a3),
                            pack2(one, one), pack2(one, 0));
        }
        Bf[j] = *reinterpret_cast<bf16x8*>(&bv);
    }

    const f32x16 zero16 = {0,0,0,0,0,0,0,0,0,0,0,0,0,0,0,0};
    float dmin0 = FLT_MAX, dmin1 = FLT_MAX, dmin2 = FLT_MAX, dmin3 = FLT_MAX;

    // ---- scan this wave's 512 points: 16 tiles x (1 load + 4 MFMA + folds),
    //      manual stagger, prefetch-1, <=3 live C-sets ----
    const uint4* __restrict__ Abase = (half ? hi : lo) + (dbBase + w * 512 + col);

    bf16x8 a = *reinterpret_cast<const bf16x8*>(Abase);
    for (int pt = 0; pt < 16; ++pt) {
        const bf16x8 acur = a;
        if (pt < 15)
            a = *reinterpret_cast<const bf16x8*>(Abase + (pt + 1) * 32);
        f32x16 c0 = __builtin_amdgcn_mfma_f32_32x32x16_bf16(acur, Bf[0], zero16, 0, 0, 0);
        f32x16 c1 = __builtin_amdgcn_mfma_f32_32x32x16_bf16(acur, Bf[1], zero16, 0, 0, 0);
        dmin0 = fold16(c0, dmin0);
        c0 = __builtin_amdgcn_mfma_f32_32x32x16_bf16(acur, Bf[2], zero16, 0, 0, 0);
        dmin1 = fold16(c1, dmin1);
        c1 = __builtin_amdgcn_mfma_f32_32x32x16_bf16(acur, Bf[3], zero16, 0, 0, 0);
        dmin2 = fold16(c0, dmin2);
        dmin3 = fold16(c1, dmin3);
    }

    // ---- combine row-halves (lane vs lane+32 hold disjoint point rows) ----
    float dmin[4] = {dmin0, dmin1, dmin2, dmin3};
    #pragma unroll
    for (int j = 0; j < 4; ++j) {
        const float v = fminf(dmin[j], __shfl_xor(dmin[j], 32));
        if (!half) part[w][j * 32 + col] = v;
    }
    __syncthreads();

    // ---- final: min over 8 wave-partials, add q^2, sqrt, sum-reduce ----
    float dist = 0.0f;
    if (t < 128) {
        float m = part[0][t];
        #pragma unroll
        for (int ww = 1; ww < 8; ++ww)
            m = fminf(m, part[ww][t]);
        const float q2 = q2arr[qBase + t];
        dist = sqrtf(fmaxf(q2 + m, 0.0f));
    }
    #pragma unroll
    for (int off = 32; off > 0; off >>= 1)
        dist += __shfl_down(dist, off);
    if (t < 128 && (t & 63) == 0)
        atomicAdd(out, dist * (1.0f / 134217728.0f));   // 1/(8*4096*4096)
}

extern "C" void kernel_launch(void* const* d_in, const int* in_sizes, int n_in,
                              void* d_out, int out_size, void* d_ws, size_t ws_size,
                              hipStream_t stream) {
    const float* s1 = (const float*)d_in[0];
    const float* s2 = (const float*)d_in[1];
    float* out = (float*)d_out;

    char* ws = (char*)d_ws;                         // needs 2.25 MB
    uint4* lo = (uint4*)ws;                         // [65536] x 16 B = 1 MB
    uint4* hi = (uint4*)(ws + (1u << 20));          // 1 MB
    float* q2 = (float*)(ws + (2u << 20));          // 256 KB

    hipMemsetAsync(out, 0, sizeof(float), stream);  // d_out poisoned 0xAA each call
    pack_pts<<<dim3(NTOT / 256), dim3(256), 0, stream>>>(s1, s2, lo, hi, q2);
    chamfer_main<<<dim3(512), dim3(512), 0, stream>>>(lo, hi, q2, out);
}

// Round 6
// 73.819 us; speedup vs baseline: 1.0860x; 1.0860x over previous
//
#include <hip/hip_runtime.h>
#include <math.h>
#include <float.h>

// ChamferLoss: set1/set2 [8, 4096, 3] fp32 -> scalar
// out = (sum of per-point min dists, both directions) / (8*4096*4096)
//
// v6b: identical to v6 (single fused kernel, LDS-resident MFMA) with the
// last-iteration uninitialized-prefetch UB fixed. v6 never ran (container
// infra failure), so the R4 theory/prediction stand:
// v4/v5 post-mortem: the packed A-fragment stream (64 MB, written by
// pack_pts on other XCDs) was a latency-bound Infinity-Cache stream
// (~2.6 TB/s eff) -> ~25us kernel. Here each block reads its raw 48 KB DB
// once (coalesced), packs fp16 hi/lo fragments into 64 KB LDS, and the hot
// loop runs entirely from LDS.
//
// d^2 = q2 + [p2 - 2 q.p] via one v_mfma_f32_32x32x16_f16 per 32x32 tile:
//   A (point rows), lanes 0-31 (k0-7):  [phx,phy,phz, plx,ply,plz, p2h,p2l]
//   A lanes 32-63 (k8-15): same 16B masked to [phx,phy,phz, 0,0,0,0,0]
//   B (query cols), k0-7:  [-2qhx,-2qhy,-2qhz, -2qhx,-2qhy,-2qhz, 1, 1]
//   B k8-15:               [-2qlx,-2qly,-2qlz, 0,0,0,0,0]
// = p2h+p2l - 2qh.(ph+pl) - 2ql.ph   (drops ql.pl ~ 2^-24 rel: negligible).
// Lane->k-half mapping (lanes 0-31 = k0-7) HW-validated by v4 passing.
// C/D: col=lane&31 = query; min over rows folds regs + shfl_xor(32).
//
// Structure: 512 blocks x 512 thr; block = (dir, batch, 128-query chunk).
// 8 waves scan 512 points each (16 tiles x [1 ds_read_b128 + 4 MFMA + folds]).
// LDS 64 KB -> 2 blocks/CU: block B+1's stage overlaps block B's MFMA loop.
// part[] aliases the frag buffer after a barrier (keeps static LDS at 64 KB).

#define NPTS 4096

typedef __attribute__((ext_vector_type(8)))  _Float16 f16x8;
typedef __attribute__((ext_vector_type(16))) float    f32x16;

static __device__ __forceinline__ unsigned h2u(_Float16 h) {
    return (unsigned)__builtin_bit_cast(unsigned short, h);
}
static __device__ __forceinline__ unsigned pack2(unsigned a, unsigned b) {
    return (a & 0xFFFFu) | (b << 16);
}

__device__ __forceinline__ float fold16(const f32x16 c, float m) {
    // 8 x v_min3_f32: min over this column's 16 point-rows + running min
    m = fminf(fminf(c[0],  c[1]),  m);
    m = fminf(fminf(c[2],  c[3]),  m);
    m = fminf(fminf(c[4],  c[5]),  m);
    m = fminf(fminf(c[6],  c[7]),  m);
    m = fminf(fminf(c[8],  c[9]),  m);
    m = fminf(fminf(c[10], c[11]), m);
    m = fminf(fminf(c[12], c[13]), m);
    m = fminf(fminf(c[14], c[15]), m);
    return m;
}

__global__ __launch_bounds__(512, 4)
void chamfer_fused(const float* __restrict__ set1,
                   const float* __restrict__ set2,
                   float* __restrict__ out)
{
    __shared__ uint4 frag[NPTS];          // 64 KB; first 4 KB reused as part[]

    const int blk = blockIdx.x;           // 0..511
    const int dir = blk >> 8;             // 0: q=set1 db=set2, 1: swapped
    const int rem = blk & 255;
    const int b   = rem >> 5;             // batch 0..7
    const int qc  = rem & 31;             // 128-query chunk 0..31

    const float* __restrict__ Q  = (dir ? set2 : set1) + (size_t)b * NPTS * 3;
    const float* __restrict__ DB = (dir ? set1 : set2) + (size_t)b * NPTS * 3;

    const int t    = threadIdx.x;
    const int lane = t & 63;
    const int w    = t >> 6;              // wave 0..7
    const int col  = lane & 31;
    const int half = lane >> 5;           // 0: k0-7, 1: k8-15
    const int qbase = qc * 128;

    // ---- stage: each thread packs points {t + 512k} into LDS ----
    // (strided ownership -> ds_write_b128 addresses are lane-consecutive)
    #pragma unroll
    for (int k = 0; k < 8; ++k) {
        const int p = t + 512 * k;
        const float x = DB[3 * p + 0];
        const float y = DB[3 * p + 1];
        const float z = DB[3 * p + 2];
        const _Float16 hx = (_Float16)x, hy = (_Float16)y, hz = (_Float16)z;
        const _Float16 lx = (_Float16)(x - (float)hx);
        const _Float16 ly = (_Float16)(y - (float)hy);
        const _Float16 lz = (_Float16)(z - (float)hz);
        const float p2 = fmaf(x, x, fmaf(y, y, z * z));
        const _Float16 p2h = (_Float16)p2;
        const _Float16 p2l = (_Float16)(p2 - (float)p2h);
        frag[p] = make_uint4(pack2(h2u(hx),  h2u(hy)),
                             pack2(h2u(hz),  h2u(lx)),
                             pack2(h2u(ly),  h2u(lz)),
                             pack2(h2u(p2h), h2u(p2l)));
    }

    // ---- B-frags: 4 query tiles, built per-lane from raw floats ----
    f16x8 Bf[4];
    #pragma unroll
    for (int j = 0; j < 4; ++j) {
        const float* qp = Q + (size_t)(qbase + j * 32 + col) * 3;
        const float qx = qp[0], qy = qp[1], qz = qp[2];
        const _Float16 hx = (_Float16)qx, hy = (_Float16)qy, hz = (_Float16)qz;
        uint4 bv;
        if (!half) {
            const unsigned mx = h2u((_Float16)(-2.0f * (float)hx));
            const unsigned my = h2u((_Float16)(-2.0f * (float)hy));
            const unsigned mz = h2u((_Float16)(-2.0f * (float)hz));
            const unsigned one = 0x3C00u;               // fp16 1.0
            bv = make_uint4(pack2(mx, my), pack2(mz, mx),
                            pack2(my, mz), pack2(one, one));
        } else {
            const unsigned mx = h2u((_Float16)(-2.0f * (qx - (float)hx)));
            const unsigned my = h2u((_Float16)(-2.0f * (qy - (float)hy)));
            const unsigned mz = h2u((_Float16)(-2.0f * (qz - (float)hz)));
            bv = make_uint4(pack2(mx, my), pack2(mz, 0), 0u, 0u);
        }
        Bf[j] = __builtin_bit_cast(f16x8, bv);
    }

    __syncthreads();

    // ---- hot loop: this wave's 512 points, 16 tiles, all from LDS ----
    const unsigned mY  = half ? 0x0000FFFFu : 0xFFFFFFFFu;  // keep phz, drop plx
    const unsigned mZW = half ? 0u          : 0xFFFFFFFFu;  // drop ply..p2l
    const uint4* __restrict__ fb = frag + w * 512 + col;

    const f32x16 z16 = {0,0,0,0,0,0,0,0,0,0,0,0,0,0,0,0};
    float dm0 = FLT_MAX, dm1 = FLT_MAX, dm2 = FLT_MAX, dm3 = FLT_MAX;

    uint4 u = fb[0];
    for (int pt = 0; pt < 16; ++pt) {
        uint4 un = u;
        if (pt < 15) un = fb[(pt + 1) * 32];              // prefetch next tile
        const uint4 am = make_uint4(u.x, u.y & mY, u.z & mZW, u.w & mZW);
        const f16x8 av = __builtin_bit_cast(f16x8, am);
        f32x16 c0 = __builtin_amdgcn_mfma_f32_32x32x16_f16(av, Bf[0], z16, 0, 0, 0);
        f32x16 c1 = __builtin_amdgcn_mfma_f32_32x32x16_f16(av, Bf[1], z16, 0, 0, 0);
        dm0 = fold16(c0, dm0);
        c0 = __builtin_amdgcn_mfma_f32_32x32x16_f16(av, Bf[2], z16, 0, 0, 0);
        dm1 = fold16(c1, dm1);
        c1 = __builtin_amdgcn_mfma_f32_32x32x16_f16(av, Bf[3], z16, 0, 0, 0);
        dm2 = fold16(c0, dm2);
        dm3 = fold16(c1, dm3);
        u = un;
    }

    // ---- combine row-halves; reuse frag LDS as part[8][128] ----
    float dmin[4] = {dm0, dm1, dm2, dm3};
    __syncthreads();                      // all frag reads complete
    float* part = (float*)frag;           // 4 KB of the 64 KB buffer
    #pragma unroll
    for (int j = 0; j < 4; ++j) {
        const float v = fminf(dmin[j], __shfl_xor(dmin[j], 32));
        if (!half) part[w * 128 + j * 32 + col] = v;
    }
    __syncthreads();

    // ---- final: min over 8 waves, add q2 (fp32 exact), sqrt, sum ----
    float dist = 0.0f;
    if (t < 128) {
        float m = part[t];
        #pragma unroll
        for (int ww = 1; ww < 8; ++ww)
            m = fminf(m, part[ww * 128 + t]);
        const float* qp = Q + (size_t)(qbase + t) * 3;
        const float q2 = fmaf(qp[0], qp[0], fmaf(qp[1], qp[1], qp[2] * qp[2]));
        dist = sqrtf(fmaxf(q2 + m, 0.0f));
    }
    #pragma unroll
    for (int off = 32; off > 0; off >>= 1)
        dist += __shfl_down(dist, off);
    if (t < 128 && (t & 63) == 0)
        atomicAdd(out, dist * (1.0f / 134217728.0f));   // 1/(8*4096*4096)
}

extern "C" void kernel_launch(void* const* d_in, const int* in_sizes, int n_in,
                              void* d_out, int out_size, void* d_ws, size_t ws_size,
                              hipStream_t stream) {
    const float* s1 = (const float*)d_in[0];
    const float* s2 = (const float*)d_in[1];
    float* out = (float*)d_out;

    hipMemsetAsync(out, 0, sizeof(float), stream);  // d_out poisoned 0xAA each call
    chamfer_fused<<<dim3(512), dim3(512), 0, stream>>>(s1, s2, out);
}